// Round 5
// baseline (6625.257 us; speedup 1.0000x reference)
//
#include <hip/hip_runtime.h>
#include <hip/hip_bf16.h>

// Problem dims (fixed by the reference)
#define B_    64
#define T_    2048
#define DIN_  64
#define H_    256
#define DOUT_ 64

// tanh via exp2-backed __expf: 1 - 2/(1+e^{2x}); exact saturation, ~1e-7 abs err.
__device__ __forceinline__ float tanh_fast(float x) {
    float e = __expf(2.0f * x);
    return 1.0f - 2.0f / (e + 1.0f);
}

// ---------------------------------------------------------------------------
// Recurrence: one block per batch element. Thread j owns hidden unit j.
// W_hh row j (256 f32) + W_ih row j (64 f32) live in registers (~350 VGPR,
// 1 wave/SIMD). h (256 f32) and x (64 f32) live in LDS; all reads are
// wave-uniform float4 (broadcast, conflict-free). 2 barriers/step.
// 4 rotating accumulators: consecutive FMAs never share an accumulator, so
// the single resident wave runs at issue rate (2 cyc/FMA), not dep-latency.
// ---------------------------------------------------------------------------
__global__ __launch_bounds__(256, 1) void rnn_recurrence(
    const float* __restrict__ x,      // [B,T,DIN]
    const float* __restrict__ h0,     // [1,H]
    const float* __restrict__ Wih,    // [H,DIN]
    const float* __restrict__ Whh,    // [H,H]
    const float* __restrict__ bih,    // [H]
    const float* __restrict__ bhh,    // [H]
    float* __restrict__ hidd)         // [B,T,H] out
{
    const int b = blockIdx.x;
    const int j = threadIdx.x;  // 0..255

    __shared__ __align__(16) float hs[H_];
    __shared__ __align__(16) float xs[DIN_];

    // ---- load W_hh row j into registers (one-time) ----
    float whh[H_];
    {
        const float4* wr = reinterpret_cast<const float4*>(Whh + (size_t)j * H_);
        #pragma unroll
        for (int q = 0; q < H_ / 4; ++q) {
            float4 u = wr[q];
            whh[4*q+0] = u.x; whh[4*q+1] = u.y;
            whh[4*q+2] = u.z; whh[4*q+3] = u.w;
        }
    }
    // ---- load W_ih row j into registers ----
    float wih[DIN_];
    {
        const float4* wr = reinterpret_cast<const float4*>(Wih + (size_t)j * DIN_);
        #pragma unroll
        for (int q = 0; q < DIN_ / 4; ++q) {
            float4 u = wr[q];
            wih[4*q+0] = u.x; wih[4*q+1] = u.y;
            wih[4*q+2] = u.z; wih[4*q+3] = u.w;
        }
    }

    const float bias = bih[j] + bhh[j];
    hs[j] = h0[j];   // h0 is [1,H], broadcast over batch

    const float* xg = x + (size_t)b * T_ * DIN_;
    float* hg = hidd + (size_t)b * T_ * H_;

    float xnext = (j < DIN_) ? xg[j] : 0.0f;  // prefetch t=0

    for (int t = 0; t < T_; ++t) {
        if (j < DIN_) xs[j] = xnext;
        __syncthreads();                               // xs + hs(prev) ready
        if (j < DIN_ && t + 1 < T_) xnext = xg[(t + 1) * DIN_ + j];

        // 4 independent accumulator chains (a0..a3): consecutive FMAs rotate
        // accumulators -> same-acc reuse distance = 4 instrs (8 cyc) > 4 cyc
        // FMA latency. Throughput-bound at 2 cyc/FMA even with 1 wave/SIMD.
        float a0 = bias, a1 = 0.0f, a2 = 0.0f, a3 = 0.0f;

        // input projection: dot(W_ih[j,:], x_t)
        #pragma unroll
        for (int q = 0; q < DIN_ / 4; ++q) {
            float4 xv = reinterpret_cast<const float4*>(xs)[q];
            a0 = fmaf(wih[4*q+0], xv.x, a0);
            a1 = fmaf(wih[4*q+1], xv.y, a1);
            a2 = fmaf(wih[4*q+2], xv.z, a2);
            a3 = fmaf(wih[4*q+3], xv.w, a3);
        }
        // recurrent matvec: dot(W_hh[j,:], h_{t-1})
        #pragma unroll
        for (int q = 0; q < H_ / 4; ++q) {
            float4 hv = reinterpret_cast<const float4*>(hs)[q];
            a0 = fmaf(whh[4*q+0], hv.x, a0);
            a1 = fmaf(whh[4*q+1], hv.y, a1);
            a2 = fmaf(whh[4*q+2], hv.z, a2);
            a3 = fmaf(whh[4*q+3], hv.w, a3);
        }
        float hn = tanh_fast((a0 + a1) + (a2 + a3));

        __syncthreads();                               // all hs reads done
        hs[j] = hn;
        hg[(size_t)t * H_ + j] = hn;
    }
}

// ---------------------------------------------------------------------------
// Output projection: out[n,o] = dot(hidd[n,:], W_out[o,:]) + b_out[o]
// Block = 32 output cols x 16 bt-rows. LDS 48.2KB (wsf 32x257 + hsr 16x256):
//   - under the 64KB static limit, 3 blocks/CU co-resident.
//   - wsf pad 257: bank=(o+k)%32, 32 lanes with distinct o -> all distinct
//     banks; half-waves share addresses -> broadcast. Conflict-free.
//   - hsr reads are float4 at 2 distinct addresses per wave (2-way = free).
// ---------------------------------------------------------------------------
#define OCH_ 32   // output columns per block
#define RCH_ 16   // bt-rows per block

__global__ __launch_bounds__(256) void rnn_out(
    const float* __restrict__ hidd,   // [B*T, H]
    const float* __restrict__ Wout,   // [DOUT, H]
    const float* __restrict__ bout,   // [DOUT]
    float* __restrict__ out)          // [B*T, DOUT]
{
    __shared__ __align__(16) float wsf[OCH_][H_ + 1];   // [32][257] = 32.1KB
    __shared__ __align__(16) float hsr[RCH_][H_];       // [16][256] = 16KB

    const int tid = threadIdx.x;
    const int ohalf  = blockIdx.x & 1;                  // which 32 of the 64 cols
    const size_t row0 = (size_t)(blockIdx.x >> 1) * RCH_;

    // stage W_out half (32x256, 32 elems/thread, coalesced)
    for (int i = tid; i < OCH_ * H_; i += 256) {
        int o = i >> 8, k = i & (H_ - 1);
        wsf[o][k] = Wout[(size_t)(o + OCH_ * ohalf) * H_ + k];
    }
    // stage RCH_ hidden rows (16x256, 16 elems/thread, coalesced)
    for (int i = tid; i < RCH_ * H_; i += 256) {
        int r = i >> 8, k = i & (H_ - 1);
        hsr[r][k] = hidd[(row0 + (size_t)r) * H_ + k];
    }
    __syncthreads();

    const int ol = tid & (OCH_ - 1);       // local output column 0..31
    const int rg = tid >> 5;               // row group 0..7
    const int og = ol + OCH_ * ohalf;      // global output column
    const float bo = bout[og];

    #pragma unroll
    for (int rr = 0; rr < RCH_ / 8; ++rr) {
        const int r = rg + 8 * rr;
        float a0 = bo, a1 = 0.0f, a2 = 0.0f, a3 = 0.0f;
        #pragma unroll
        for (int q = 0; q < H_ / 4; ++q) {
            float4 hv = reinterpret_cast<const float4*>(&hsr[r][0])[q];
            a0 = fmaf(wsf[ol][4*q+0], hv.x, a0);
            a1 = fmaf(wsf[ol][4*q+1], hv.y, a1);
            a2 = fmaf(wsf[ol][4*q+2], hv.z, a2);
            a3 = fmaf(wsf[ol][4*q+3], hv.w, a3);
        }
        out[(row0 + (size_t)r) * DOUT_ + og] = (a0 + a1) + (a2 + a3);
    }
}

extern "C" void kernel_launch(void* const* d_in, const int* in_sizes, int n_in,
                              void* d_out, int out_size, void* d_ws, size_t ws_size,
                              hipStream_t stream) {
    const float* x    = (const float*)d_in[0];
    const float* h0   = (const float*)d_in[1];
    const float* Wih  = (const float*)d_in[2];
    const float* Whh  = (const float*)d_in[3];
    const float* bih  = (const float*)d_in[4];
    const float* bhh  = (const float*)d_in[5];
    const float* Wout = (const float*)d_in[6];
    const float* bout = (const float*)d_in[7];

    float* outputs = (float*)d_out;                       // [B,T,DOUT]
    float* hiddens = outputs + (size_t)B_ * T_ * DOUT_;   // [B,T,H]

    rnn_recurrence<<<B_, 256, 0, stream>>>(x, h0, Wih, Whh, bih, bhh, hiddens);

    const int nrows = B_ * T_;                            // 131072
    rnn_out<<<(nrows / RCH_) * 2, 256, 0, stream>>>(hiddens, Wout, bout, outputs);
}